// Round 1
// baseline (2484.207 us; speedup 1.0000x reference)
//
#include <hip/hip_runtime.h>
#include <hip/hip_bf16.h>
#include <math.h>

// ---------------------------------------------------------------------------
// VisionExpertAttention on MI355X (gfx950)
// Pipeline:
//   1. cast hidden + 4 weight mats f32->bf16 into ws
//   2. vm mask kernel (vision iff tt[l]==1 && tt[l+1]==1)
//   3. qkv GEMM (m97 recipe: 128x128 tile, BK=32, global_load_lds w=16,
//      mfma_f32_16x16x32_bf16), run per expert with row-predicated epilogue
//   4. rope+split -> q,k [BH,L,D] bf16 ; vtrans -> v [BH,D,L] bf16
//   5. flash attention (KT=64, online softmax, P via LDS C->A layout xform)
//   6. dense GEMM per expert, predicated, fp32 out
// ---------------------------------------------------------------------------

typedef __bf16 bf16_t;
typedef __bf16 bf16x8 __attribute__((ext_vector_type(8)));
typedef __bf16 bf16x4 __attribute__((ext_vector_type(4)));
typedef float  f32x4  __attribute__((ext_vector_type(4)));

#define BSZ   2
#define SEQ   2048
#define NTOK  (BSZ * SEQ)     // 4096
#define HID   4096
#define NH    32
#define HD    128
#define QKV3  (3 * HID)       // 12288

__device__ __forceinline__ void gld_lds16(const bf16_t* g, bf16_t* l) {
  __builtin_amdgcn_global_load_lds(
      (const __attribute__((address_space(1))) unsigned int*)g,
      (__attribute__((address_space(3))) unsigned int*)l, 16, 0, 0);
}

// ---------------------------------------------------------------- cast f32->bf16
__global__ __launch_bounds__(256) void castk(const float* __restrict__ in,
                                             bf16_t* __restrict__ out,
                                             long long n) {
  long long i = ((long long)blockIdx.x * 256 + threadIdx.x) * 4;
  if (i >= n) return;
  float4 v = *(const float4*)(in + i);
  bf16x4 o;
  o[0] = (bf16_t)v.x; o[1] = (bf16_t)v.y; o[2] = (bf16_t)v.z; o[3] = (bf16_t)v.w;
  *(bf16x4*)(out + i) = o;
}

// ---------------------------------------------------------------- vision mask
__global__ __launch_bounds__(256) void mask_kernel(const int* __restrict__ tt,
                                                   int* __restrict__ vm) {
  int t = blockIdx.x * 256 + threadIdx.x;
  if (t >= NTOK) return;
  int l = t & (SEQ - 1);
  int v = 0;
  if (l < SEQ - 1) v = (tt[t] == 1 && tt[t + 1] == 1) ? 1 : 0;
  vm[t] = v;
}

// ---------------------------------------------------------------- GEMM C = A @ B^T
// A [M,K] bf16 row-major, B [N,K] bf16 row-major. Epilogue writes only rows
// where vm[row]==sel. OUT_F32: 1 -> float C, 0 -> bf16 C.
template <int OUT_F32>
__global__ __launch_bounds__(256) void gemm_bt_mask(
    const bf16_t* __restrict__ A, const bf16_t* __restrict__ B,
    void* __restrict__ Cout, int M, int N, int K,
    const int* __restrict__ vm, int sel) {
  __shared__ bf16_t As[128 * 32];
  __shared__ bf16_t Bs[128 * 32];
  const int tid = threadIdx.x;
  const int bm = blockIdx.x, bn = blockIdx.y;
  const int wv = tid >> 6, lane = tid & 63, lr = lane & 15, quad = lane >> 4;
  const int wm = (wv >> 1) * 64, wn = (wv & 1) * 64;

  // staging: slot s -> row s/4, 16B chunk s%4 of [128][32] bf16 tile
  const int r0 = tid >> 2;
  const int c0 = (tid & 3) * 8;
  const bf16_t* a0 = A + (size_t)(bm * 128 + r0) * K + c0;
  const bf16_t* a1 = A + (size_t)(bm * 128 + r0 + 64) * K + c0;
  const bf16_t* b0 = B + (size_t)(bn * 128 + r0) * K + c0;
  const bf16_t* b1 = B + (size_t)(bn * 128 + r0 + 64) * K + c0;
  bf16_t* asD0 = &As[(tid & ~63) * 8];
  bf16_t* asD1 = &As[(256 + (tid & ~63)) * 8];
  bf16_t* bsD0 = &Bs[(tid & ~63) * 8];
  bf16_t* bsD1 = &Bs[(256 + (tid & ~63)) * 8];

  f32x4 acc[4][4] = {};

  for (int kt = 0; kt < K; kt += 32) {
    gld_lds16(a0 + kt, asD0);
    gld_lds16(a1 + kt, asD1);
    gld_lds16(b0 + kt, bsD0);
    gld_lds16(b1 + kt, bsD1);
    __syncthreads();
    bf16x8 af[4], bfr[4];
#pragma unroll
    for (int i = 0; i < 4; i++)
      af[i] = *(const bf16x8*)&As[(wm + i * 16 + lr) * 32 + quad * 8];
#pragma unroll
    for (int j = 0; j < 4; j++)
      bfr[j] = *(const bf16x8*)&Bs[(wn + j * 16 + lr) * 32 + quad * 8];
#pragma unroll
    for (int i = 0; i < 4; i++)
#pragma unroll
      for (int j = 0; j < 4; j++)
        acc[i][j] = __builtin_amdgcn_mfma_f32_16x16x32_bf16(af[i], bfr[j],
                                                            acc[i][j], 0, 0, 0);
    __syncthreads();
  }

  // epilogue: C row = quad*4+reg (within 16-tile), col = lane&15
#pragma unroll
  for (int i = 0; i < 4; i++) {
#pragma unroll
    for (int r = 0; r < 4; r++) {
      int row = bm * 128 + wm + i * 16 + quad * 4 + r;
      if (vm[row] != sel) continue;
      size_t rowoff = (size_t)row * N + bn * 128 + wn + lr;
#pragma unroll
      for (int j = 0; j < 4; j++) {
        if (OUT_F32)
          ((float*)Cout)[rowoff + j * 16] = acc[i][j][r];
        else
          ((bf16_t*)Cout)[rowoff + j * 16] = (bf16_t)acc[i][j][r];
      }
    }
  }
}

// ---------------------------------------------------------------- RoPE + q/k split
// mixed [NTOK, 12288] bf16 -> qbuf,kbuf [BH, SEQ, HD] bf16 with RoPE applied.
__global__ __launch_bounds__(256) void rope_split(
    const bf16_t* __restrict__ mixed, const int* __restrict__ pos_ids,
    bf16_t* __restrict__ qbuf, bf16_t* __restrict__ kbuf) {
  int idx = blockIdx.x * 256 + threadIdx.x;   // NTOK*NH*64 threads
  int d2 = idx & 63;
  int h = (idx >> 6) & 31;
  int token = idx >> 11;
  int b = token >> 11;
  int l = token & (SEQ - 1);
  int pos = pos_ids[token];
  // inv_freq = 10000^(-d2/64) ; angle = pos * inv_freq
  float inv = expf((float)d2 * -0.14391156831212787f);  // -ln(10000)/64
  float ang = (float)pos * inv;
  float c = cosf(ang), s = sinf(ang);

  const bf16_t* row = mixed + (size_t)token * QKV3;
  float q1 = (float)row[h * HD + d2];
  float q2 = (float)row[h * HD + d2 + 64];
  float k1 = (float)row[HID + h * HD + d2];
  float k2 = (float)row[HID + h * HD + d2 + 64];

  size_t base = ((size_t)(b * NH + h) * SEQ + l) * HD;
  qbuf[base + d2]      = (bf16_t)(q1 * c - q2 * s);
  qbuf[base + d2 + 64] = (bf16_t)(q2 * c + q1 * s);
  kbuf[base + d2]      = (bf16_t)(k1 * c - k2 * s);
  kbuf[base + d2 + 64] = (bf16_t)(k2 * c + k1 * s);
}

// ---------------------------------------------------------------- V transpose
// mixed v-section -> vbuf [BH, HD, SEQ] bf16 (keys contiguous per d for PV MFMA B-frag)
__global__ __launch_bounds__(256) void vtrans(const bf16_t* __restrict__ mixed,
                                              bf16_t* __restrict__ vbuf) {
  __shared__ bf16_t tile[64][130];  // +2 pad: write-phase column reads stay conflict-free
  const int bh = blockIdx.x;        // 0..63
  const int lt = blockIdx.y;        // 0..31 (l-tile of 64)
  const int b = bh >> 5, h = bh & 31;
  const int tid = threadIdx.x;
#pragma unroll
  for (int i = 0; i < 32; i++) {
    int s = i * 256 + tid;        // 0..8191
    int l = s >> 7, d = s & 127;  // read coalesced along d
    size_t token = (size_t)b * SEQ + lt * 64 + l;
    tile[l][d] = mixed[token * QKV3 + 2 * HID + h * HD + d];
  }
  __syncthreads();
#pragma unroll
  for (int i = 0; i < 32; i++) {
    int s = i * 256 + tid;
    int d = s >> 6, l = s & 63;   // write coalesced along l
    vbuf[((size_t)bh * HD + d) * SEQ + lt * 64 + l] = tile[l][d];
  }
}

// ---------------------------------------------------------------- flash attention
// grid (BH=64, SEQ/128=16), 256 threads = 4 waves, wave owns 32 q rows.
__global__ __launch_bounds__(256) void attn_fwd(
    const bf16_t* __restrict__ qb, const bf16_t* __restrict__ kb,
    const bf16_t* __restrict__ vb, bf16_t* __restrict__ ctx) {
  __shared__ bf16_t Ks[64 * 128];      // [key][d]
  __shared__ bf16_t Vs[128 * 64];      // [d][key]
  __shared__ bf16_t Ps[4 * 32 * 64];   // per-wave P [32 q][64 key]
  const int bh = blockIdx.x, qt = blockIdx.y;
  const int b = bh >> 5, h = bh & 31;
  const int tid = threadIdx.x;
  const int wv = tid >> 6, lane = tid & 63, lr = lane & 15, quad = lane >> 4;
  const int qrow0 = qt * 128 + wv * 32;

  const bf16_t* qbase = qb + (size_t)bh * SEQ * HD;
  const bf16_t* kbase = kb + (size_t)bh * SEQ * HD;
  const bf16_t* vbase = vb + (size_t)bh * HD * SEQ;

  // Q fragments held in registers for the whole block row
  bf16x8 qf[2][4];
#pragma unroll
  for (int i = 0; i < 2; i++)
#pragma unroll
    for (int ds = 0; ds < 4; ds++)
      qf[i][ds] = *(const bf16x8*)(qbase + (size_t)(qrow0 + i * 16 + lr) * HD +
                                   ds * 32 + quad * 8);

  f32x4 O[2][8] = {};
  float mst[2][4], lst[2][4];
#pragma unroll
  for (int i = 0; i < 2; i++)
#pragma unroll
    for (int r = 0; r < 4; r++) { mst[i][r] = -1e30f; lst[i][r] = 0.f; }

  const float scale = 0.08838834764831845f;  // 1/sqrt(128)

  for (int kt = 0; kt < SEQ / 64; kt++) {
    const bf16_t* ksrc = kbase + (size_t)kt * 64 * HD;
    const bf16_t* vsrc = vbase + kt * 64;
#pragma unroll
    for (int inst = 0; inst < 4; inst++) {
      int s = inst * 256 + tid;  // 16B chunk id, 0..1023
      gld_lds16(ksrc + (size_t)(s >> 4) * HD + (s & 15) * 8,
                &Ks[(inst * 256 + (tid & ~63)) * 8]);
      gld_lds16(vsrc + (size_t)(s >> 3) * SEQ + (s & 7) * 8,
                &Vs[(inst * 256 + (tid & ~63)) * 8]);
    }
    __syncthreads();

    // S = Q @ K^T  (per wave: [32 q][64 key])
    f32x4 S[2][4] = {};
#pragma unroll
    for (int ds = 0; ds < 4; ds++) {
      bf16x8 kf[4];
#pragma unroll
      for (int n = 0; n < 4; n++)
        kf[n] = *(const bf16x8*)&Ks[(n * 16 + lr) * HD + ds * 32 + quad * 8];
#pragma unroll
      for (int i = 0; i < 2; i++)
#pragma unroll
        for (int n = 0; n < 4; n++)
          S[i][n] = __builtin_amdgcn_mfma_f32_16x16x32_bf16(qf[i][ds], kf[n],
                                                            S[i][n], 0, 0, 0);
    }

    bf16_t* pw = &Ps[wv * 32 * 64];
#pragma unroll
    for (int i = 0; i < 2; i++) {
      float rmax[4];
#pragma unroll
      for (int r = 0; r < 4; r++) {
        float m = -1e30f;
#pragma unroll
        for (int n = 0; n < 4; n++) {
          S[i][n][r] *= scale;
          m = fmaxf(m, S[i][n][r]);
        }
#pragma unroll
        for (int off = 1; off < 16; off <<= 1)
          m = fmaxf(m, __shfl_xor(m, off, 64));
        rmax[r] = m;
      }
#pragma unroll
      for (int r = 0; r < 4; r++) {
        float mnew = fmaxf(mst[i][r], rmax[r]);
        float alpha = __expf(mst[i][r] - mnew);
        mst[i][r] = mnew;
        float rsum = 0.f;
#pragma unroll
        for (int n = 0; n < 4; n++) {
          float p = __expf(S[i][n][r] - mnew);
          S[i][n][r] = p;
          rsum += p;
        }
#pragma unroll
        for (int off = 1; off < 16; off <<= 1) rsum += __shfl_xor(rsum, off, 64);
        lst[i][r] = lst[i][r] * alpha + rsum;
#pragma unroll
        for (int n = 0; n < 8; n++) O[i][n][r] *= alpha;
        // write P (C-layout -> LDS row-major [q][key]) for A-frag reads
#pragma unroll
        for (int n = 0; n < 4; n++)
          pw[(i * 16 + quad * 4 + r) * 64 + n * 16 + lr] = (bf16_t)S[i][n][r];
      }
    }

    // O += P @ V   (contraction over 64 keys, 2 k-steps of 32)
#pragma unroll
    for (int ks = 0; ks < 2; ks++) {
      bf16x8 pf[2], vf[8];
#pragma unroll
      for (int i = 0; i < 2; i++)
        pf[i] = *(const bf16x8*)&pw[(i * 16 + lr) * 64 + ks * 32 + quad * 8];
#pragma unroll
      for (int n = 0; n < 8; n++)
        vf[n] = *(const bf16x8*)&Vs[(n * 16 + lr) * 64 + ks * 32 + quad * 8];
#pragma unroll
      for (int i = 0; i < 2; i++)
#pragma unroll
        for (int n = 0; n < 8; n++)
          O[i][n] = __builtin_amdgcn_mfma_f32_16x16x32_bf16(pf[i], vf[n],
                                                            O[i][n], 0, 0, 0);
    }
    __syncthreads();
  }

  // epilogue: normalize and write ctx [token][h*128+d] bf16
#pragma unroll
  for (int i = 0; i < 2; i++)
#pragma unroll
    for (int r = 0; r < 4; r++) {
      float inv = 1.0f / lst[i][r];
      size_t tok = (size_t)b * SEQ + qt * 128 + wv * 32 + i * 16 + quad * 4 + r;
#pragma unroll
      for (int n = 0; n < 8; n++)
        ctx[tok * HID + h * HD + n * 16 + lr] = (bf16_t)(O[i][n][r] * inv);
    }
}

// ---------------------------------------------------------------- launch
extern "C" void kernel_launch(void* const* d_in, const int* in_sizes, int n_in,
                              void* d_out, int out_size, void* d_ws, size_t ws_size,
                              hipStream_t stream) {
  const float* hs  = (const float*)d_in[0];
  const int*   tt  = (const int*)d_in[1];
  const int*   pos = (const int*)d_in[2];
  // d_in[3] attention_mask: all zeros, unused by the reference math
  const float* wvq = (const float*)d_in[4];
  const float* wlq = (const float*)d_in[5];
  const float* wvd = (const float*)d_in[6];
  const float* wld = (const float*)d_in[7];
  float* out = (float*)d_out;

  char* ws = (char*)d_ws;
  size_t off = 0;
  auto alloc = [&](size_t bytes) -> char* {
    char* p = ws + off;
    off += (bytes + 255) & ~(size_t)255;
    return p;
  };
  bf16_t* hsb   = (bf16_t*)alloc((size_t)NTOK * HID * 2);
  bf16_t* wvqb  = (bf16_t*)alloc((size_t)QKV3 * HID * 2);
  bf16_t* wlqb  = (bf16_t*)alloc((size_t)QKV3 * HID * 2);
  bf16_t* wvdb  = (bf16_t*)alloc((size_t)HID * HID * 2);
  bf16_t* wldb  = (bf16_t*)alloc((size_t)HID * HID * 2);
  bf16_t* mixed = (bf16_t*)alloc((size_t)NTOK * QKV3 * 2);
  bf16_t* qbuf  = (bf16_t*)alloc((size_t)NTOK * HID * 2);
  bf16_t* kbuf  = (bf16_t*)alloc((size_t)NTOK * HID * 2);
  bf16_t* vbuf  = (bf16_t*)alloc((size_t)NTOK * HID * 2);
  int*    vm    = (int*)alloc((size_t)NTOK * 4);
  bf16_t* ctx   = mixed;  // mixed is dead after rope_split/vtrans; reuse for ctx

  auto cast = [&](const float* in, bf16_t* o, long long n) {
    castk<<<dim3((unsigned)((n + 1023) / 1024)), dim3(256), 0, stream>>>(in, o, n);
  };
  cast(hs,  hsb,  (long long)NTOK * HID);
  cast(wvq, wvqb, (long long)QKV3 * HID);
  cast(wlq, wlqb, (long long)QKV3 * HID);
  cast(wvd, wvdb, (long long)HID * HID);
  cast(wld, wldb, (long long)HID * HID);

  mask_kernel<<<dim3(NTOK / 256), dim3(256), 0, stream>>>(tt, vm);

  // routed QKV: both experts, predicated epilogue (vision=1, language=0)
  gemm_bt_mask<0><<<dim3(NTOK / 128, QKV3 / 128), dim3(256), 0, stream>>>(
      hsb, wvqb, mixed, NTOK, QKV3, HID, vm, 1);
  gemm_bt_mask<0><<<dim3(NTOK / 128, QKV3 / 128), dim3(256), 0, stream>>>(
      hsb, wlqb, mixed, NTOK, QKV3, HID, vm, 0);

  rope_split<<<dim3((NTOK * NH * 64) / 256), dim3(256), 0, stream>>>(mixed, pos,
                                                                     qbuf, kbuf);
  vtrans<<<dim3(BSZ * NH, SEQ / 64), dim3(256), 0, stream>>>(mixed, vbuf);

  attn_fwd<<<dim3(BSZ * NH, SEQ / 128), dim3(256), 0, stream>>>(qbuf, kbuf, vbuf,
                                                                ctx);

  // routed dense out (fp32)
  gemm_bt_mask<1><<<dim3(NTOK / 128, HID / 128), dim3(256), 0, stream>>>(
      ctx, wvdb, out, NTOK, HID, HID, vm, 1);
  gemm_bt_mask<1><<<dim3(NTOK / 128, HID / 128), dim3(256), 0, stream>>>(
      ctx, wldb, out, NTOK, HID, HID, vm, 0);
}

// Round 2
// 2163.137 us; speedup vs baseline: 1.1484x; 1.1484x over previous
//
#include <hip/hip_runtime.h>
#include <hip/hip_bf16.h>
#include <math.h>

// ---------------------------------------------------------------------------
// VisionExpertAttention on MI355X (gfx950) — round 2
//   * expert ROUTING via device-side scan + gathered rows (halves GEMM FLOPs
//     vs compute-both-and-predicate; graph-capture safe: grid fixed at 33
//     M-tiles, per-tile expert chosen from device counter)
//   * XOR-swizzled LDS layouts: GEMM frag reads 8-way -> 2-way conflicts,
//     attention Ks/Vs/Ps reads 16-way -> 2-way (m136: 2-way is free)
// ---------------------------------------------------------------------------

typedef __bf16 bf16_t;
typedef __bf16 bf16x8 __attribute__((ext_vector_type(8)));
typedef __bf16 bf16x4 __attribute__((ext_vector_type(4)));
typedef float  f32x4  __attribute__((ext_vector_type(4)));

#define BSZ   2
#define SEQ   2048
#define NTOK  (BSZ * SEQ)     // 4096
#define MPAD  (NTOK + 128)    // 4224 gathered rows (vision padded to 128)
#define HID   4096
#define NH    32
#define HD    128
#define QKV3  (3 * HID)       // 12288

__device__ __forceinline__ void gld_lds16(const bf16_t* g, bf16_t* l) {
  __builtin_amdgcn_global_load_lds(
      (const __attribute__((address_space(1))) unsigned int*)g,
      (__attribute__((address_space(3))) unsigned int*)l, 16, 0, 0);
}

// ---------------------------------------------------------------- cast f32->bf16
__global__ __launch_bounds__(256) void castk(const float* __restrict__ in,
                                             bf16_t* __restrict__ out,
                                             long long n) {
  long long i = ((long long)blockIdx.x * 256 + threadIdx.x) * 4;
  if (i >= n) return;
  float4 v = *(const float4*)(in + i);
  bf16x4 o;
  o[0] = (bf16_t)v.x; o[1] = (bf16_t)v.y; o[2] = (bf16_t)v.z; o[3] = (bf16_t)v.w;
  *(bf16x4*)(out + i) = o;
}

// ------------------------------------------------- cast + gather hidden rows
__global__ __launch_bounds__(256) void cast_gather(const float* __restrict__ in,
                                                   bf16_t* __restrict__ out,
                                                   const int* __restrict__ ginv) {
  long long i = ((long long)blockIdx.x * 256 + threadIdx.x) * 4;
  int token = (int)(i >> 12);        // HID = 4096
  int col = (int)(i & 4095);
  float4 v = *(const float4*)(in + i);
  bf16x4 o;
  o[0] = (bf16_t)v.x; o[1] = (bf16_t)v.y; o[2] = (bf16_t)v.z; o[3] = (bf16_t)v.w;
  *(bf16x4*)(out + (size_t)ginv[token] * HID + col) = o;
}

// ---------------------------------------------------------------- routing scan
// vision iff tt[l]==1 && tt[l+1]==1 (l < SEQ-1). vision tokens -> rows
// [0,nv), pad to 128; language -> [nvpad, nvpad+nl). perm_src[dst]=token or
// -1 (pad), ginv[token]=dst, meta[0]=nvpad/128 (# vision M-tiles).
__global__ __launch_bounds__(1024) void scan_kernel(const int* __restrict__ tt,
                                                    int* __restrict__ perm_src,
                                                    int* __restrict__ ginv,
                                                    int* __restrict__ meta) {
  __shared__ int sums[1024];
  const int t = threadIdx.x;
  for (int i = t; i < MPAD; i += 1024) perm_src[i] = -1;
  int v[4], s = 0;
#pragma unroll
  for (int j = 0; j < 4; j++) {
    int tok = t * 4 + j;
    int l = tok & (SEQ - 1);
    int vis = (l < SEQ - 1) && (tt[tok] == 1) && (tt[tok + 1] == 1);
    v[j] = vis; s += vis;
  }
  sums[t] = s;
  __syncthreads();
  for (int off = 1; off < 1024; off <<= 1) {
    int x = sums[t];
    int y = (t >= off) ? sums[t - off] : 0;
    __syncthreads();
    sums[t] = x + y;
    __syncthreads();
  }
  const int nv = sums[1023];
  const int nvpad = (nv + 127) & ~127;
  int pv = sums[t] - s;  // vision count strictly before this thread's tokens
#pragma unroll
  for (int j = 0; j < 4; j++) {
    int tok = t * 4 + j;
    int dst;
    if (v[j]) { dst = pv; pv++; }
    else      { dst = nvpad + (tok - pv); }
    perm_src[dst] = tok;
    ginv[tok] = dst;
  }
  if (t == 0) meta[0] = nvpad >> 7;
}

// ------------------------------------------- routed GEMM C = A_g @ B_e^T
// A [MPAD,K] gathered bf16; B chosen per M-tile (vision tiles first).
// Epilogue scatters row perm_src[row_g] (skip -1). Swizzled LDS: chunk of
// row r stored at chunkpos ^ ((r>>1)&3)  ->  2-way (free) frag reads.
template <int OUT_F32>
__global__ __launch_bounds__(256) void gemm_routed(
    const bf16_t* __restrict__ A, const bf16_t* __restrict__ Bv,
    const bf16_t* __restrict__ Bl, void* __restrict__ Cout, int N, int K,
    const int* __restrict__ perm_src, const int* __restrict__ meta) {
  __shared__ bf16_t As[128 * 32];
  __shared__ bf16_t Bs[128 * 32];
  const int tid = threadIdx.x;
  const int bm = blockIdx.x, bn = blockIdx.y;
  const bf16_t* __restrict__ B = (bm < meta[0]) ? Bv : Bl;
  const int wv = tid >> 6, lane = tid & 63, lr = lane & 15, quad = lane >> 4;
  const int wm = (wv >> 1) * 64, wn = (wv & 1) * 64;

  // staging: LDS slot tid = row tid>>2, chunkpos tid&3; load the global
  // chunk that belongs there under the swizzle
  const int r0 = tid >> 2;
  const int c0 = ((tid & 3) ^ ((tid >> 3) & 3)) * 8;
  const bf16_t* a0 = A + (size_t)(bm * 128 + r0) * K + c0;
  const bf16_t* a1 = A + (size_t)(bm * 128 + r0 + 64) * K + c0;
  const bf16_t* b0 = B + (size_t)(bn * 128 + r0) * K + c0;
  const bf16_t* b1 = B + (size_t)(bn * 128 + r0 + 64) * K + c0;
  bf16_t* asD0 = &As[(tid & ~63) * 8];
  bf16_t* asD1 = &As[(256 + (tid & ~63)) * 8];
  bf16_t* bsD0 = &Bs[(tid & ~63) * 8];
  bf16_t* bsD1 = &Bs[(256 + (tid & ~63)) * 8];

  // fragment read chunkpos: quad ^ ((row>>1)&3); row = wm+i*16+lr with
  // wm+i*16 a multiple of 16 -> (row>>1)&3 == (lr>>1)&3, lane-constant.
  const int pp = (quad ^ ((lr >> 1) & 3)) * 8;

  f32x4 acc[4][4] = {};

  for (int kt = 0; kt < K; kt += 32) {
    gld_lds16(a0 + kt, asD0);
    gld_lds16(a1 + kt, asD1);
    gld_lds16(b0 + kt, bsD0);
    gld_lds16(b1 + kt, bsD1);
    __syncthreads();
    bf16x8 af[4], bfr[4];
#pragma unroll
    for (int i = 0; i < 4; i++)
      af[i] = *(const bf16x8*)&As[(wm + i * 16 + lr) * 32 + pp];
#pragma unroll
    for (int j = 0; j < 4; j++)
      bfr[j] = *(const bf16x8*)&Bs[(wn + j * 16 + lr) * 32 + pp];
#pragma unroll
    for (int i = 0; i < 4; i++)
#pragma unroll
      for (int j = 0; j < 4; j++)
        acc[i][j] = __builtin_amdgcn_mfma_f32_16x16x32_bf16(af[i], bfr[j],
                                                            acc[i][j], 0, 0, 0);
    __syncthreads();
  }

  // epilogue: C row = quad*4+reg, col = lane&15; scatter to original token
#pragma unroll
  for (int i = 0; i < 4; i++) {
#pragma unroll
    for (int r = 0; r < 4; r++) {
      int rowg = bm * 128 + wm + i * 16 + quad * 4 + r;
      int src = perm_src[rowg];
      if (src < 0) continue;
      size_t rowoff = (size_t)src * N + bn * 128 + wn + lr;
#pragma unroll
      for (int j = 0; j < 4; j++) {
        if (OUT_F32)
          ((float*)Cout)[rowoff + j * 16] = acc[i][j][r];
        else
          ((bf16_t*)Cout)[rowoff + j * 16] = (bf16_t)acc[i][j][r];
      }
    }
  }
}

// ---------------------------------------------------------------- RoPE + q/k split
__global__ __launch_bounds__(256) void rope_split(
    const bf16_t* __restrict__ mixed, const int* __restrict__ pos_ids,
    bf16_t* __restrict__ qbuf, bf16_t* __restrict__ kbuf) {
  int idx = blockIdx.x * 256 + threadIdx.x;
  int d2 = idx & 63;
  int h = (idx >> 6) & 31;
  int token = idx >> 11;
  int b = token >> 11;
  int l = token & (SEQ - 1);
  int pos = pos_ids[token];
  float inv = expf((float)d2 * -0.14391156831212787f);  // -ln(10000)/64
  float ang = (float)pos * inv;
  float c = cosf(ang), s = sinf(ang);

  const bf16_t* row = mixed + (size_t)token * QKV3;
  float q1 = (float)row[h * HD + d2];
  float q2 = (float)row[h * HD + d2 + 64];
  float k1 = (float)row[HID + h * HD + d2];
  float k2 = (float)row[HID + h * HD + d2 + 64];

  size_t base = ((size_t)(b * NH + h) * SEQ + l) * HD;
  qbuf[base + d2]      = (bf16_t)(q1 * c - q2 * s);
  qbuf[base + d2 + 64] = (bf16_t)(q2 * c + q1 * s);
  kbuf[base + d2]      = (bf16_t)(k1 * c - k2 * s);
  kbuf[base + d2 + 64] = (bf16_t)(k2 * c + k1 * s);
}

// ---------------------------------------------------------------- V transpose
__global__ __launch_bounds__(256) void vtrans(const bf16_t* __restrict__ mixed,
                                              bf16_t* __restrict__ vbuf) {
  __shared__ bf16_t tile[64][130];
  const int bh = blockIdx.x;
  const int lt = blockIdx.y;
  const int b = bh >> 5, h = bh & 31;
  const int tid = threadIdx.x;
#pragma unroll
  for (int i = 0; i < 32; i++) {
    int s = i * 256 + tid;
    int l = s >> 7, d = s & 127;
    size_t token = (size_t)b * SEQ + lt * 64 + l;
    tile[l][d] = mixed[token * QKV3 + 2 * HID + h * HD + d];
  }
  __syncthreads();
#pragma unroll
  for (int i = 0; i < 32; i++) {
    int s = i * 256 + tid;
    int d = s >> 6, l = s & 63;
    vbuf[((size_t)bh * HD + d) * SEQ + lt * 64 + l] = tile[l][d];
  }
}

// ---------------------------------------------------------------- flash attention
// Swizzled LDS: chunk (16B) of row r stored at chunkpos ^ (r&7).
// ctx written in GATHERED row order (ginv) for the routed dense GEMM.
__global__ __launch_bounds__(256) void attn_fwd(
    const bf16_t* __restrict__ qb, const bf16_t* __restrict__ kb,
    const bf16_t* __restrict__ vb, bf16_t* __restrict__ ctxg,
    const int* __restrict__ ginv) {
  __shared__ bf16_t Ks[64 * 128];      // [key][d], swizzled
  __shared__ bf16_t Vs[128 * 64];      // [d][key], swizzled
  __shared__ bf16_t Ps[4 * 32 * 64];   // per-wave P [32 q][64 key], swizzled
  const int bh = blockIdx.x, qt = blockIdx.y;
  const int b = bh >> 5, h = bh & 31;
  const int tid = threadIdx.x;
  const int wv = tid >> 6, lane = tid & 63, lr = lane & 15, quad = lane >> 4;
  const int qrow0 = qt * 128 + wv * 32;

  const bf16_t* qbase = qb + (size_t)bh * SEQ * HD;
  const bf16_t* kbase = kb + (size_t)bh * SEQ * HD;
  const bf16_t* vbase = vb + (size_t)bh * HD * SEQ;

  bf16x8 qf[2][4];
#pragma unroll
  for (int i = 0; i < 2; i++)
#pragma unroll
    for (int ds = 0; ds < 4; ds++)
      qf[i][ds] = *(const bf16x8*)(qbase + (size_t)(qrow0 + i * 16 + lr) * HD +
                                   ds * 32 + quad * 8);

  f32x4 O[2][8] = {};
  float mst[2][4], lst[2][4];
#pragma unroll
  for (int i = 0; i < 2; i++)
#pragma unroll
    for (int r = 0; r < 4; r++) { mst[i][r] = -1e30f; lst[i][r] = 0.f; }

  const float scale = 0.08838834764831845f;  // 1/sqrt(128)
  const int l7 = lr & 7;

  for (int kt = 0; kt < SEQ / 64; kt++) {
    const bf16_t* ksrc = kbase + (size_t)kt * 64 * HD;
    const bf16_t* vsrc = vbase + kt * 64;
#pragma unroll
    for (int inst = 0; inst < 4; inst++) {
      int s = inst * 256 + tid;
      int krow = s >> 4, kg = (s & 15) ^ (krow & 7);
      gld_lds16(ksrc + (size_t)krow * HD + kg * 8,
                &Ks[(inst * 256 + (tid & ~63)) * 8]);
      int vrow = s >> 3, vg = (s & 7) ^ (vrow & 7);
      gld_lds16(vsrc + (size_t)vrow * SEQ + vg * 8,
                &Vs[(inst * 256 + (tid & ~63)) * 8]);
    }
    __syncthreads();

    // S = Q @ K^T
    f32x4 S[2][4] = {};
#pragma unroll
    for (int ds = 0; ds < 4; ds++) {
      bf16x8 kf[4];
#pragma unroll
      for (int n = 0; n < 4; n++)
        kf[n] = *(const bf16x8*)&Ks[(n * 16 + lr) * HD +
                                    ((ds * 4 + quad) ^ l7) * 8];
#pragma unroll
      for (int i = 0; i < 2; i++)
#pragma unroll
        for (int n = 0; n < 4; n++)
          S[i][n] = __builtin_amdgcn_mfma_f32_16x16x32_bf16(qf[i][ds], kf[n],
                                                            S[i][n], 0, 0, 0);
    }

    bf16_t* pw = &Ps[wv * 32 * 64];
#pragma unroll
    for (int i = 0; i < 2; i++) {
      float rmax[4];
#pragma unroll
      for (int r = 0; r < 4; r++) {
        float m = -1e30f;
#pragma unroll
        for (int n = 0; n < 4; n++) {
          S[i][n][r] *= scale;
          m = fmaxf(m, S[i][n][r]);
        }
#pragma unroll
        for (int off = 1; off < 16; off <<= 1)
          m = fmaxf(m, __shfl_xor(m, off, 64));
        rmax[r] = m;
      }
#pragma unroll
      for (int r = 0; r < 4; r++) {
        float mnew = fmaxf(mst[i][r], rmax[r]);
        float alpha = __expf(mst[i][r] - mnew);
        mst[i][r] = mnew;
        float rsum = 0.f;
#pragma unroll
        for (int n = 0; n < 4; n++) {
          float p = __expf(S[i][n][r] - mnew);
          S[i][n][r] = p;
          rsum += p;
        }
#pragma unroll
        for (int off = 1; off < 16; off <<= 1) rsum += __shfl_xor(rsum, off, 64);
        lst[i][r] = lst[i][r] * alpha + rsum;
#pragma unroll
        for (int n = 0; n < 8; n++) O[i][n][r] *= alpha;
        int row = i * 16 + quad * 4 + r;
#pragma unroll
        for (int n = 0; n < 4; n++) {
          int e = n * 16 + lr;
          pw[row * 64 + (((e >> 3) ^ (row & 7)) * 8) + (e & 7)] =
              (bf16_t)S[i][n][r];
        }
      }
    }

    // O += P @ V
#pragma unroll
    for (int ks = 0; ks < 2; ks++) {
      bf16x8 pf[2], vf[8];
#pragma unroll
      for (int i = 0; i < 2; i++)
        pf[i] = *(const bf16x8*)&pw[(i * 16 + lr) * 64 +
                                    ((ks * 4 + quad) ^ l7) * 8];
#pragma unroll
      for (int n = 0; n < 8; n++)
        vf[n] = *(const bf16x8*)&Vs[(n * 16 + lr) * 64 +
                                    ((ks * 4 + quad) ^ l7) * 8];
#pragma unroll
      for (int i = 0; i < 2; i++)
#pragma unroll
        for (int n = 0; n < 8; n++)
          O[i][n] = __builtin_amdgcn_mfma_f32_16x16x32_bf16(pf[i], vf[n],
                                                            O[i][n], 0, 0, 0);
    }
    __syncthreads();
  }

  // epilogue: normalize, write ctx in GATHERED order
#pragma unroll
  for (int i = 0; i < 2; i++)
#pragma unroll
    for (int r = 0; r < 4; r++) {
      float inv = 1.0f / lst[i][r];
      int tok = b * SEQ + qt * 128 + wv * 32 + i * 16 + quad * 4 + r;
      size_t dst = (size_t)ginv[tok] * HID + h * HD;
#pragma unroll
      for (int n = 0; n < 8; n++)
        ctxg[dst + n * 16 + lr] = (bf16_t)(O[i][n][r] * inv);
    }
}

// ---------------------------------------------------------------- launch
extern "C" void kernel_launch(void* const* d_in, const int* in_sizes, int n_in,
                              void* d_out, int out_size, void* d_ws, size_t ws_size,
                              hipStream_t stream) {
  const float* hs  = (const float*)d_in[0];
  const int*   tt  = (const int*)d_in[1];
  const int*   pos = (const int*)d_in[2];
  // d_in[3] attention_mask: all zeros, unused
  const float* wvq = (const float*)d_in[4];
  const float* wlq = (const float*)d_in[5];
  const float* wvd = (const float*)d_in[6];
  const float* wld = (const float*)d_in[7];
  float* out = (float*)d_out;

  char* ws = (char*)d_ws;
  size_t off = 0;
  auto alloc = [&](size_t bytes) -> char* {
    char* p = ws + off;
    off += (bytes + 255) & ~(size_t)255;
    return p;
  };
  bf16_t* hsg   = (bf16_t*)alloc((size_t)MPAD * HID * 2);   // gathered hidden
  bf16_t* wvqb  = (bf16_t*)alloc((size_t)QKV3 * HID * 2);
  bf16_t* wlqb  = (bf16_t*)alloc((size_t)QKV3 * HID * 2);
  bf16_t* wvdb  = (bf16_t*)alloc((size_t)HID * HID * 2);
  bf16_t* wldb  = (bf16_t*)alloc((size_t)HID * HID * 2);
  bf16_t* mixed = (bf16_t*)alloc((size_t)NTOK * QKV3 * 2);  // token order
  bf16_t* qbuf  = (bf16_t*)alloc((size_t)NTOK * HID * 2);
  bf16_t* kbuf  = (bf16_t*)alloc((size_t)NTOK * HID * 2);
  bf16_t* vbuf  = (bf16_t*)alloc((size_t)NTOK * HID * 2);
  int* perm_src = (int*)alloc((size_t)MPAD * 4);
  int* ginv     = (int*)alloc((size_t)NTOK * 4);
  int* meta     = (int*)alloc(256);
  bf16_t* ctxg  = mixed;  // mixed dead after rope/vtrans; reuse (MPAD rows fit)

  scan_kernel<<<dim3(1), dim3(1024), 0, stream>>>(tt, perm_src, ginv, meta);

  cast_gather<<<dim3(NTOK * HID / 1024), dim3(256), 0, stream>>>(hs, hsg, ginv);
  auto cast = [&](const float* in, bf16_t* o, long long n) {
    castk<<<dim3((unsigned)((n + 1023) / 1024)), dim3(256), 0, stream>>>(in, o, n);
  };
  cast(wvq, wvqb, (long long)QKV3 * HID);
  cast(wlq, wlqb, (long long)QKV3 * HID);
  cast(wvd, wvdb, (long long)HID * HID);
  cast(wld, wldb, (long long)HID * HID);

  // routed QKV: one GEMM, expert chosen per M-tile, scatter to token order
  gemm_routed<0><<<dim3(MPAD / 128, QKV3 / 128), dim3(256), 0, stream>>>(
      hsg, wvqb, wlqb, mixed, QKV3, HID, perm_src, meta);

  rope_split<<<dim3((NTOK * NH * 64) / 256), dim3(256), 0, stream>>>(mixed, pos,
                                                                     qbuf, kbuf);
  vtrans<<<dim3(BSZ * NH, SEQ / 64), dim3(256), 0, stream>>>(mixed, vbuf);

  attn_fwd<<<dim3(BSZ * NH, SEQ / 128), dim3(256), 0, stream>>>(qbuf, kbuf, vbuf,
                                                                ctxg, ginv);

  // routed dense out (fp32), scatter rows to d_out token order
  gemm_routed<1><<<dim3(MPAD / 128, HID / 128), dim3(256), 0, stream>>>(
      ctxg, wvdb, wldb, out, HID, HID, perm_src, meta);
}